// Round 13
// baseline (112.565 us; speedup 1.0000x reference)
//
#include <hip/hip_runtime.h>

#define D 256
#define NV 512
#define NT 512
#define KCAT 1536          // 6 concatenated K=256 segments (split-bf16 GEMM)
#define EPS 1e-8f
#define HALF_EPS 5e-9f
#define LN2 0.69314718055994531f

// Taylor of lgamma at 2.5 (row_stats deg-6 path)
#define C0 0.28468287047291920f
#define C1 0.70315664064524320f
#define C2 0.24517887805011740f
#define C3 (-0.03936734194028790f)
#define C4 0.00932941036738560f
#define C5 (-0.00261463332905590f)
#define C6 0.00080356830356760f
// Chebyshev-economized quadratic on s in [-1/2,1/2]
#define C0E 0.28460998445f
#define C1E 0.69577526404f
#define C2E 0.24751123064f

#define LSTRIDE 68

typedef float f32x4 __attribute__((ext_vector_type(4)));
typedef short s16x8 __attribute__((ext_vector_type(8)));
typedef unsigned short u16;

__device__ __forceinline__ float rcpf(float x) { return __builtin_amdgcn_rcpf(x); }

__device__ __forceinline__ u16 f2bf(float f) {   // RNE f32 -> bf16 bits
    unsigned int u = __float_as_uint(f);
    return (u16)((u + 0x7FFFu + ((u >> 16) & 1u)) >> 16);
}
__device__ __forceinline__ float bf2f(u16 b) {
    return __uint_as_float(((unsigned int)b) << 16);
}

__device__ __forceinline__ float stirling_lgamma(float y) { // y >= 4
    float r = rcpf(y), r2 = r * r;
    float ln = LN2 * __log2f(y);
    return (y - 0.5f) * ln - y + 0.91893853320467f
         + r * (0.08333333333f - 0.00277777778f * r2);
}

__device__ __forceinline__ float stirling_digamma(float y) { // y >= 4
    float r = rcpf(y), r2 = r * r;
    return LN2 * __log2f(y) - 0.5f * r - r2 * (0.08333333333f - 0.00833333333f * r2);
}

// Fragment-order transposed GEMM operand layout:
// element (global k, row) lives at ((k>>3)*512 + row)*8 + (k&7).
__device__ __forceinline__ int tidx(int s, int d, int rr) {
    return (((s << 5) + (d >> 3)) * 512 + rr) * 8 + (d & 7);
}

// One block per row. Scalars float4 [S, A, dgS, Q]; fragment-order split-bf16.
// A = 0.5*(lgamma(S') - sum lgamma(x')) + 0.25*sum(x'*psi);  Q = sum (0.5x')^2.
// psi_mod = psi(x') - C2E*x' folds the v.t cross term into the dot GEMM.
__global__ __launch_bounds__(256) void row_stats(
    const float* __restrict__ va, const float* __restrict__ ta,
    u16* __restrict__ AcatT, u16* __restrict__ BcatT,
    float* __restrict__ rv, float* __restrict__ rt)
{
    int r = blockIdx.x;
    bool isV = (r < NV);
    int rr = isV ? r : r - NV;
    const float* row = (isV ? va : ta) + rr * D;
    float* sc = (isV ? rv : rt) + rr * 4;
    u16* cat = isV ? BcatT : AcatT;

    int d = threadIdx.x;
    float raw = row[d];
    float x = raw + EPS;

    float y = x + 4.0f;
    float ry = rcpf(y), ry2 = ry * ry;
    float psi = LN2 * __log2f(y) - 0.5f * ry - ry2 * (0.08333333333f - 0.00833333333f * ry2);
    psi -= rcpf(x) + rcpf(x + 1.0f) + rcpf(x + 2.0f) + rcpf(x + 3.0f);

    float s = x - 0.5f;
    float q6 = fmaf(C6, s, C5);
    q6 = fmaf(q6, s, C4); q6 = fmaf(q6, s, C3); q6 = fmaf(q6, s, C2); q6 = fmaf(q6, s, C1);
    float g = fmaf(q6, s, C0) - LN2 * __log2f(x * (x + 1.0f));

    // split-bf16 operands
    float pm = psi - C2E * x;
    u16 xh = f2bf(x);  u16 xl = f2bf(x - bf2f(xh));
    u16 ph = f2bf(pm); u16 pl = f2bf(pm - bf2f(ph));
    if (isV) {  // B side
        cat[tidx(0,d,rr)] = ph; cat[tidx(1,d,rr)] = pl; cat[tidx(2,d,rr)] = ph;
        cat[tidx(3,d,rr)] = xh; cat[tidx(4,d,rr)] = xl; cat[tidx(5,d,rr)] = xh;
    } else {    // A side
        cat[tidx(0,d,rr)] = xh; cat[tidx(1,d,rr)] = xh; cat[tidx(2,d,rr)] = xl;
        cat[tidx(3,d,rr)] = ph; cat[tidx(4,d,rr)] = ph; cat[tidx(5,d,rr)] = pl;
    }

    float vh = fmaf(0.5f, raw, HALF_EPS);
    float S = raw, G = g, P = x * psi, Q = vh * vh;
    #pragma unroll
    for (int off = 32; off > 0; off >>= 1) {
        S += __shfl_down(S, off, 64);
        G += __shfl_down(G, off, 64);
        P += __shfl_down(P, off, 64);
        Q += __shfl_down(Q, off, 64);
    }
    __shared__ float red[4][4];
    int wid = d >> 6, lane = d & 63;
    if (lane == 0) { red[0][wid] = S; red[1][wid] = G; red[2][wid] = P; red[3][wid] = Q; }
    __syncthreads();
    if (d == 0) {
        float S4 = red[0][0] + red[0][1] + red[0][2] + red[0][3];
        float G4 = red[1][0] + red[1][1] + red[1][2] + red[1][3];
        float P4 = red[2][0] + red[2][1] + red[2][2] + red[2][3];
        float Q4 = red[3][0] + red[3][1] + red[3][2] + red[3][3];
        float Se = S4 + 256.0f * EPS;
        float A = 0.5f * (stirling_lgamma(Se) - G4) + 0.25f * P4;
        *(float4*)sc = make_float4(S4, A, stirling_digamma(Se), Q4);
    }
}

// 32x32 tile, 2x2 outputs per thread, grid (16,16,4): z covers d in
// [64z,64z+64) and K-quarter of the GEMM. 1024 blocks = 4/CU (16 waves/CU),
// 21.4 KB LDS, ONE barrier. LDS reads per output-elem HALVED vs R11/R12
// (4 b128 per CITER feed 4 pair-groups). Waves own one 16x16 MFMA quadrant.
__global__ __launch_bounds__(256, 4) void jsd_pairs(
    const float* __restrict__ va, const float* __restrict__ ta,
    const u16* __restrict__ AcatT, const u16* __restrict__ BcatT,
    const float* __restrict__ rv, const float* __restrict__ rt,
    float* __restrict__ out)
{
    __shared__ float vs[32 * LSTRIDE];
    __shared__ float ts[32 * LSTRIDE];
    __shared__ float red[4 * 256];

    const int tid = threadIdx.x;
    const int j0 = blockIdx.x * 32;      // v rows (output cols)
    const int i0 = blockIdx.y * 32;      // t rows (output rows)
    const int z  = blockIdx.z;           // 0..3: d in [64z,64z+64)
    const int w = tid >> 6, l = tid & 63;

    // ---- issue staging loads first (coalesced: 16 lanes span one row seg) ----
    int srow[2], sc4[2];
    float4 sv[2], st4[2];
    #pragma unroll
    for (int k = 0; k < 2; ++k) {
        int q = tid + (k << 8);          // 0..511
        srow[k] = q >> 4;                // 0..31
        sc4[k]  = q & 15;                // float4 col in 64-d quarter
        sv[k]  = *(const float4*)(va + (j0 + srow[k]) * D + (z << 6) + (sc4[k] << 2));
        st4[k] = *(const float4*)(ta + (i0 + srow[k]) * D + (z << 6) + (sc4[k] << 2));
    }

    // ---- MFMA: wave w owns quadrant (iq,jq); K-chunks [48z, 48z+48) (8-elem units) ----
    {
        const int iq = w >> 1, jq = w & 1;
        f32x4 acc = {0.0f, 0.0f, 0.0f, 0.0f};
        const u16* Ap = AcatT + ((((z * 48) + (l >> 4)) * 512) + i0 + 16 * iq + (l & 15)) * 8;
        const u16* Bp = BcatT + ((((z * 48) + (l >> 4)) * 512) + j0 + 16 * jq + (l & 15)) * 8;
        #pragma unroll
        for (int stp = 0; stp < 12; ++stp) {
            s16x8 a = *(const s16x8*)(Ap + stp * 16384);   // +4 8-chunks
            s16x8 b = *(const s16x8*)(Bp + stp * 16384);
            acc = __builtin_amdgcn_mfma_f32_16x16x32_bf16(a, b, acc, 0, 0, 0);
        }
        int base = w * 256 + ((l >> 4) << 6) + (l & 15);   // row=(l>>4)*4+r, col=l&15
        red[base]      = acc[0];
        red[base + 16] = acc[1];
        red[base + 32] = acc[2];
        red[base + 48] = acc[3];
    }

    // ---- write staging to LDS ----
    #define HALVE4(P) { P.x = fmaf(0.5f,P.x,HALF_EPS); P.y = fmaf(0.5f,P.y,HALF_EPS); \
                        P.z = fmaf(0.5f,P.z,HALF_EPS); P.w = fmaf(0.5f,P.w,HALF_EPS); }
    #pragma unroll
    for (int k = 0; k < 2; ++k) {
        HALVE4(sv[k]); HALVE4(st4[k]);
        *(float4*)(vs + srow[k] * LSTRIDE + (sc4[k] << 2)) = sv[k];
        *(float4*)(ts + srow[k] * LSTRIDE + (sc4[k] << 2)) = st4[k];
    }
    __syncthreads();                     // one barrier: staging + red[] published

    const int tj2 = tid & 15;            // col pair base (j, j+16)
    const int ti2 = tid >> 4;            // row pair base (i, i+16)
    const float* vpA = vs + tj2 * LSTRIDE;
    const float* vpB = vs + (tj2 + 16) * LSTRIDE;
    const float* tpP = ts + ti2 * LSTRIDE;
    const float* tpQ = ts + (ti2 + 16) * LSTRIDE;

    float aPA = 0.0f, aPB = 0.0f, aQA = 0.0f, aQB = 0.0f;

    #define PLOG(V, T, ACC) {                                                 \
        float m0 = V.x + T.x, m1 = V.y + T.y;                                 \
        float m2 = V.z + T.z, m3 = V.w + T.w;                                 \
        float w0 = fmaf(m0, m0, m0), w1 = fmaf(m1, m1, m1);                   \
        float w2 = fmaf(m2, m2, m2), w3 = fmaf(m3, m3, m3);                   \
        ACC += __log2f((w0 * w1) * (w2 * w3)); }

    #define CITER4(c) {                                                       \
        float4 vA = *(const float4*)(vpA + ((c) << 2));                       \
        float4 vB = *(const float4*)(vpB + ((c) << 2));                       \
        float4 tP = *(const float4*)(tpP + ((c) << 2));                       \
        float4 tQ = *(const float4*)(tpQ + ((c) << 2));                       \
        PLOG(vA, tP, aPA) PLOG(vB, tP, aPB)                                   \
        PLOG(vA, tQ, aQA) PLOG(vB, tQ, aQB) }

    CITER4(0)  CITER4(1)  CITER4(2)  CITER4(3)
    CITER4(4)  CITER4(5)  CITER4(6)  CITER4(7)
    CITER4(8)  CITER4(9)  CITER4(10) CITER4(11)
    CITER4(12) CITER4(13) CITER4(14) CITER4(15)

    // ---- epilogue: 2x2 outputs, combined across z via atomics ----
    #pragma unroll
    for (int ii = 0; ii < 2; ++ii) {
        #pragma unroll
        for (int jj = 0; jj < 2; ++jj) {
            float accL = (ii == 0) ? (jj == 0 ? aPA : aPB)
                                   : (jj == 0 ? aQA : aQB);
            float W = red[((ii << 1) | jj) * 256 + ti2 * 16 + tj2];
            const int i = i0 + ti2 + 16 * ii;
            const int j = j0 + tj2 + 16 * jj;
            float val = LN2 * accL + 0.25f * W;
            if (z == 0) {
                float4 RJ = *(const float4*)(rv + j * 4);
                float4 RI = *(const float4*)(rt + i * 4);
                float Sv = RJ.x, Av = RJ.y, dgSv = RJ.z, Qv = RJ.w;
                float St = RI.x, At = RI.y, dgSt = RI.z, Qt = RI.w;
                float M1 = fmaf(0.5f, Sv + St, 256.0f * EPS);
                float S1 = M1 - 128.0f;
                float quad = Qv + Qt - M1 + 64.0f;
                float SC = fmaf(C1E, S1, 256.0f * C0E) + C2E * quad
                         - stirling_lgamma(M1) + Av + At
                         + 0.25f * (Sv - St) * (dgSt - dgSv);
                val += 1.0f - SC;
            }
            atomicAdd(&out[i * 512 + j], val);
        }
    }
}

extern "C" void kernel_launch(void* const* d_in, const int* in_sizes, int n_in,
                              void* d_out, int out_size, void* d_ws, size_t ws_size,
                              hipStream_t stream) {
    const float* va = (const float*)d_in[0];
    const float* ta = (const float*)d_in[1];
    float* ws  = (float*)d_ws;
    float* rv  = ws;                                   // 512*4 f32
    float* rt  = ws + NV * 4;                          // 512*4 f32
    u16*   AcatT = (u16*)((char*)d_ws + 16384);        // 192 chunks x 512 rows x 8
    u16*   BcatT = (u16*)((char*)d_ws + 16384 + NV * KCAT * 2);
    float* out = (float*)d_out;

    hipMemsetAsync(out, 0, 512 * 512 * sizeof(float), stream);
    row_stats<<<NV + NT, 256, 0, stream>>>(va, ta, AcatT, BcatT, rv, rt);
    jsd_pairs<<<dim3(16, 16, 4), 256, 0, stream>>>(va, ta, AcatT, BcatT, rv, rt, out);
}